// Round 2
// baseline (158.019 us; speedup 1.0000x reference)
//
#include <hip/hip_runtime.h>
#include <math.h>

#define T 4096
#define C 256
#define BATCH 2
#define NH 4
#define G 32
#define CPG 8
#define EPS 1e-5f
#define LOG2E 1.4426950408889634f
// Reference applies scale=ch^-0.25 to q AND k -> logit = (q.k)/8. Fold /8 and
// log2e (exp2-domain softmax) into Q once.
#define QSCALE (0.125f * LOG2E)
#define KSPLIT 4
#define KRANGE (T / KSPLIT)
#define BH (BATCH * NH)

typedef __attribute__((ext_vector_type(8))) short bfv8;
typedef __attribute__((ext_vector_type(4))) short bfv4;
typedef __attribute__((ext_vector_type(4))) float f32x4;

static __device__ __forceinline__ short f2bf(float f) {
    union { float f; unsigned u; } v; v.f = f;
    return (short)((v.u + 0x7FFFu + ((v.u >> 16) & 1u)) >> 16);
}
static __device__ __forceinline__ short f2bf_fast(float f) {  // RN w/o tie-to-even
    union { float f; unsigned u; } v; v.f = f;
    return (short)((v.u + 0x8000u) >> 16);
}
static __device__ __forceinline__ float bf2f(short s) {
    union { float f; unsigned u; } v; v.u = ((unsigned)(unsigned short)s) << 16;
    return v.f;
}

#if __has_builtin(__builtin_amdgcn_exp2f)
#define EXP2(x) __builtin_amdgcn_exp2f(x)
#else
#define EXP2(x) exp2f(x)
#endif

// 16x16x16 bf16 MFMA: gfx90a+ "_1k" builtin, carried on gfx950. Must be used
// directly (aux-target builtin) — __has_builtin guards break the host pass.
#define MFMA16(a, b, c) __builtin_amdgcn_mfma_f32_16x16x16bf16_1k(a, b, c, 0, 0, 0)

#define AS1 __attribute__((address_space(1)))
#define AS3 __attribute__((address_space(3)))
static __device__ __forceinline__ void gll16(const void* g, void* l) {
    __builtin_amdgcn_global_load_lds((const AS1 void*)g, (AS3 void*)l, 16, 0, 0);
}

// ---------------------------------------------------------------------------
// Weight prep: fp32 -> bf16 for w_qkv [768,256] and w_proj [256,256]
// ---------------------------------------------------------------------------
__global__ __launch_bounds__(256) void prep_w(const float* __restrict__ wq,
                                              const float* __restrict__ wp,
                                              short* __restrict__ wqb,
                                              short* __restrict__ wpb) {
    int i = blockIdx.x * 256 + threadIdx.x;   // float4 index
    const int NQ = 768 * 256 / 4;
    float4 v; short* dst;
    if (i < NQ) { v = ((const float4*)wq)[i]; dst = wqb + i * 4; }
    else        { int j = i - NQ; v = ((const float4*)wp)[j]; dst = wpb + j * 4; }
    bfv4 o = { f2bf(v.x), f2bf(v.y), f2bf(v.z), f2bf(v.w) };
    *(bfv4*)dst = o;
}

// ---------------------------------------------------------------------------
// GroupNorm stats pass: grid (B*G, 4 t-splits), 256 thr.
// ---------------------------------------------------------------------------
__global__ __launch_bounds__(256) void gn_stats(const float* __restrict__ x,
                                                float* __restrict__ gnp) {
    const int blk = blockIdx.x;            // b*G+g
    const int ts  = blockIdx.y;            // 0..3
    const int b = blk / G, g = blk % G;
    const float* xp = x + ((size_t)b * C + g * CPG) * T + ts * 1024;

    const int tid = threadIdx.x;
    float s = 0.f, ss = 0.f;
    #pragma unroll
    for (int u = 0; u < CPG; u++) {
        float4 v = ((const float4*)(xp + (size_t)u * T))[tid];
        s  += v.x + v.y + v.z + v.w;
        ss += v.x*v.x + v.y*v.y + v.z*v.z + v.w*v.w;
    }
    __shared__ float rs[256], rss[256];
    rs[tid] = s; rss[tid] = ss;
    __syncthreads();
    for (int off = 128; off > 0; off >>= 1) {
        if (tid < off) { rs[tid] += rs[tid+off]; rss[tid] += rss[tid+off]; }
        __syncthreads();
    }
    if (tid == 0) {
        gnp[(blk * 4 + ts) * 2 + 0] = rs[0];
        gnp[(blk * 4 + ts) * 2 + 1] = rss[0];
    }
}

// ---------------------------------------------------------------------------
// GroupNorm normalize pass: grid (B*G, 4 t-splits), 256 thr -> bf16 xnT[b][t][c]
// ---------------------------------------------------------------------------
__global__ __launch_bounds__(256) void gn_norm(const float* __restrict__ x,
                                               const float* __restrict__ scale,
                                               const float* __restrict__ bias,
                                               const float* __restrict__ gnp,
                                               short* __restrict__ xnT) {
    const int blk = blockIdx.x;            // b*G+g
    const int ts  = blockIdx.y;            // 0..3
    const int b = blk / G, g = blk % G;
    const int c0 = g * CPG;
    const float* xp = x + ((size_t)b * C + c0) * T;

    float s = 0.f, ss = 0.f;
    #pragma unroll
    for (int i = 0; i < 4; i++) {
        s  += gnp[(blk * 4 + i) * 2 + 0];
        ss += gnp[(blk * 4 + i) * 2 + 1];
    }
    const float inv_n = 1.0f / (CPG * T);
    const float mu  = s * inv_n;
    const float var = ss * inv_n - mu * mu;
    const float rstd = rsqrtf(var + EPS);

    float sc[CPG], bi[CPG];
    #pragma unroll
    for (int u = 0; u < CPG; u++) {
        sc[u] = scale[c0+u] * rstd;
        bi[u] = bias[c0+u] - mu * sc[u];
    }

    const int t = ts * 1024 + threadIdx.x * 4;
    float vv[CPG][4];
    #pragma unroll
    for (int u = 0; u < CPG; u++) {
        float4 v = *(const float4*)&xp[(size_t)u * T + t];
        vv[u][0] = v.x * sc[u] + bi[u];
        vv[u][1] = v.y * sc[u] + bi[u];
        vv[u][2] = v.z * sc[u] + bi[u];
        vv[u][3] = v.w * sc[u] + bi[u];
    }
    #pragma unroll
    for (int j = 0; j < 4; j++) {
        bfv8 w = { f2bf(vv[0][j]), f2bf(vv[1][j]), f2bf(vv[2][j]), f2bf(vv[3][j]),
                   f2bf(vv[4][j]), f2bf(vv[5][j]), f2bf(vv[6][j]), f2bf(vv[7][j]) };
        *(bfv8*)&xnT[((size_t)b * T + t + j) * C + c0] = w;
    }
}

// ---------------------------------------------------------------------------
// qkv GEMM (bf16 MFMA, BK=64 — R9/R11/R13): grid (T/64, 12, BATCH), 256 thr.
// ---------------------------------------------------------------------------
__global__ __launch_bounds__(256) void gemm_qkv(
    const short* __restrict__ wq,    // [768][256] bf16
    const float* __restrict__ bq,    // [768]
    const short* __restrict__ xnT,   // [B][T][C] bf16
    short* __restrict__ qb, short* __restrict__ kb, short* __restrict__ vb)
{
    const int b  = blockIdx.z;
    const int t0 = blockIdx.x * 64;
    const int ot = blockIdx.y;
    const int h = ot / 3, part = ot % 3;
    const int o0 = ot * 64;

    __shared__ short sm[8192];       // A 8x512 + B 8x512 shorts (16 KiB)
    short* Ab = sm;
    short* Bb = sm + 4096;

    const int tid = threadIdx.x, lane = tid & 63, wave = tid >> 6;
    const int col = lane & 15, quad = lane >> 4;
    const short* xb = xnT + (size_t)b * T * C;

    f32x4 acc[4];
    #pragma unroll
    for (int g = 0; g < 4; g++) { acc[g][0]=0.f; acc[g][1]=0.f; acc[g][2]=0.f; acc[g][3]=0.f; }

    for (int k0 = 0; k0 < C; k0 += 64) {
        __syncthreads();
        #pragma unroll
        for (int hh = 0; hh < 2; hh++) {
            gll16(wq + (size_t)(o0 + 16*wave + col) * C + k0 + hh*32 + quad*8,
                  Ab + (hh*4 + wave) * 512);
            gll16(xb + (size_t)(t0 + 16*wave + col) * C + k0 + hh*32 + quad*8,
                  Bb + (hh*4 + wave) * 512);
        }
        __syncthreads();
        #pragma unroll
        for (int hh = 0; hh < 2; hh++) {
            bfv8 af = *(const bfv8*)(Ab + (hh*4 + wave) * 512 + lane*8);
            #pragma unroll
            for (int g = 0; g < 4; g++) {
                bfv8 bf = *(const bfv8*)(Bb + (hh*4 + g) * 512 + lane*8);
                acc[g] = __builtin_amdgcn_mfma_f32_16x16x32_bf16(af, bf, acc[g], 0, 0, 0);
            }
        }
    }

    const int olocal = 16*wave + quad*4;
    float bias_r[4];
    #pragma unroll
    for (int r = 0; r < 4; r++) bias_r[r] = bq[o0 + olocal + r];
    const size_t hd = (size_t)(b * NH + h);

    if (part < 2) {
        short* dst = (part == 0 ? qb : kb) + hd * T * 64;
        const float sc = (part == 0) ? QSCALE : 1.0f;
        #pragma unroll
        for (int g = 0; g < 4; g++) {
            int t = t0 + 16*g + col;
            bfv4 w = { f2bf((acc[g][0] + bias_r[0]) * sc),
                       f2bf((acc[g][1] + bias_r[1]) * sc),
                       f2bf((acc[g][2] + bias_r[2]) * sc),
                       f2bf((acc[g][3] + bias_r[3]) * sc) };
            *(bfv4*)&dst[(size_t)t * 64 + olocal] = w;
        }
    } else {
        short* dst = vb + hd * 64 * T;
        #pragma unroll
        for (int g = 0; g < 4; g++)
            #pragma unroll
            for (int r = 0; r < 4; r++)
                dst[(size_t)(olocal + r) * T + t0 + 16*g + col] =
                    f2bf(acc[g][r] + bias_r[r]);
    }
}

// ---------------------------------------------------------------------------
// Flash attention v10: v8's proven S^T + MFMA16 PV body, re-partitioned for
// occupancy. R1 post-mortem: v9 freed ~10us of MFMA+VALU issue with zero wall
// gain -> kernel is latency/occupancy-bound (Occ 19-33%, HBM 13%). Cause:
// grid was 512 blocks = 2/CU (50% static cap). Fix: t-tile 256 -> 128, ONE
// 16-query sub-tile per wave -> grid (32, BH, KSPLIT) = 1024 blocks = 4/CU
// = 32 waves/CU (thread-capacity full). __launch_bounds__(512,8) pins VGPR
// <= 64 so 4 blocks actually fit. Staging pattern unchanged (8 waves stage
// the 64-key K/V tile, double-buffered; single-buffer proven broken R5/R14).
// KSPLIT stays 4 -> gemm_proj combine untouched.
// ---------------------------------------------------------------------------
__global__ __launch_bounds__(512, 8) void attn_kernel(
    const short* __restrict__ qb,    // [BH][T][64] (pre-scaled by QSCALE)
    const short* __restrict__ kb,    // [BH][T][64]
    const short* __restrict__ vb,    // [BH][64][T]
    short* __restrict__ opart,       // [KSPLIT][BH][T][64] unnormalized O, bf16
    float* __restrict__ lp)          // [KSPLIT][BH][T]
{
    __shared__ short smem[16384];    // 2 x (K 8KB + V 8KB) = 32 KiB
    const int bh = blockIdx.y;
    const int ks = blockIdx.z;
    const int t0 = blockIdx.x * 128;
    const int k0base = ks * KRANGE;
    const short* kbh = kb + (size_t)bh * T * 64;
    const short* vbh = vb + (size_t)bh * 64 * T;

    const int tid  = threadIdx.x;
    const int lane = tid & 63;
    const int wave = tid >> 6;       // 0..7
    const int col  = lane & 15;
    const int quad = lane >> 4;

    // Q fragment for this wave's 16 queries (B-operand for S^T)
    const short* qrow = qb + (size_t)bh * T * 64 + (size_t)(t0 + wave*16 + col) * 64;
    bfv8 qf0 = *(const bfv8*)(qrow + quad*8);
    bfv8 qf1 = *(const bfv8*)(qrow + 32 + quad*8);

    f32x4 oacc[4];  // O^T C-layout: ch = 16g+quad*4+r, q = col
    #pragma unroll
    for (int g = 0; g < 4; g++) {
        oacc[g][0]=0.f; oacc[g][1]=0.f; oacc[g][2]=0.f; oacc[g][3]=0.f;
    }
    float lsum = 0.f;

    // V A-frag address (shorts): A[m=col][k=quad*4+j] within a 16-key chunk
    const int vq = ((quad >> 1) * 16 + col) * 8 + (quad & 1) * 4;

    // 8-wave staging: wave w stages K slot w and V slot w (one gll16 each).
    // Slot s<4: K keys 16s+col ch quad*8 / V ch 16s+col keys quad*8;
    // slot s>=4: same rows, ch/keys 32+quad*8.  (kg = w&3, hi = w>>2)
    const int kg = wave & 3, hi = wave >> 2;
    #define STAGE_KV(buf, s0)                                                  \
        {                                                                      \
            short* base = smem + (buf) * 8192;                                 \
            gll16(kbh + (size_t)((s0) + 16*kg + col) * 64 + (quad + 4*hi)*8,   \
                  base + wave * 512);                                          \
            gll16(vbh + (size_t)(16*kg + col) * T + (s0) + (quad + 4*hi)*8,    \
                  base + 4096 + wave * 512);                                   \
        }

    STAGE_KV(0, k0base)

    for (int it = 0; it < KRANGE/64; it++) {
        __syncthreads();                        // staged tile visible
        if (it + 1 < KRANGE/64) STAGE_KV((it+1) & 1, k0base + (it+1)*64)

        const short* kvb = smem + (it & 1) * 8192;

        // S^T per group of 16 keys: a[r] = logit for key 16g+quad*4+r, q=col
        bfv4 pf[4];
        #pragma unroll
        for (int g = 0; g < 4; g++) {
            bfv8 kf0 = *(const bfv8*)(kvb + g*512 + lane*8);
            bfv8 kf1 = *(const bfv8*)(kvb + (4+g)*512 + lane*8);
            f32x4 a;
            a[0]=0.f; a[1]=0.f; a[2]=0.f; a[3]=0.f;
            a = __builtin_amdgcn_mfma_f32_16x16x32_bf16(kf0, qf0, a, 0, 0, 0);
            a = __builtin_amdgcn_mfma_f32_16x16x32_bf16(kf1, qf1, a, 0, 0, 0);
            #pragma unroll
            for (int r = 0; r < 4; r++) {
                float p = EXP2(a[r]);
                lsum += p;
                pf[g][r] = f2bf_fast(p);
            }
        }

        // O^T += V P^T : per ch-group g, 4 key-chunks of 16 via K=16 MFMA
        const short* vbase = kvb + 4096;
        #pragma unroll
        for (int g = 0; g < 4; g++) {
            bfv4 v0 = *(const bfv4*)(vbase + g*512 + vq);          // keys  0..15
            bfv4 v1 = *(const bfv4*)(vbase + g*512 + vq + 256);    // keys 16..31
            bfv4 v2 = *(const bfv4*)(vbase + (4+g)*512 + vq);      // keys 32..47
            bfv4 v3 = *(const bfv4*)(vbase + (4+g)*512 + vq + 256);// keys 48..63
            oacc[g] = MFMA16(v0, pf[0], oacc[g]);
            oacc[g] = MFMA16(v1, pf[1], oacc[g]);
            oacc[g] = MFMA16(v2, pf[2], oacc[g]);
            oacc[g] = MFMA16(v3, pf[3], oacc[g]);
        }
    }

    // l: quads partition the 64 keys for query=col -> reduce across quads
    lsum += __shfl_xor(lsum, 16);
    lsum += __shfl_xor(lsum, 32);

    // epilogue: lane owns t-row (t0 + wave*16 + col), ch 16g+quad*4..+3
    const size_t rowbase = (size_t)(ks*BH + bh) * T + t0 + wave*16;
    short* opb = opart + (rowbase + col) * 64;
    #pragma unroll
    for (int g = 0; g < 4; g++) {
        bfv4 w = { f2bf(oacc[g][0]), f2bf(oacc[g][1]),
                   f2bf(oacc[g][2]), f2bf(oacc[g][3]) };
        *(bfv4*)(opb + 16*g + quad*4) = w;
    }
    if (lane < 16) {
        lp[rowbase + col] = lsum;
    }
}

// ---------------------------------------------------------------------------
// proj GEMM (bf16 MFMA, BK=64) with fused combine (R9/R11/R13): B-operand
// built from opart (sum KSPLIT partials x per-head rl). + bias + fp32 resid.
// grid (T/64, 4, BATCH).
// ---------------------------------------------------------------------------
__global__ __launch_bounds__(256) void gemm_proj(
    const short* __restrict__ wp,    // [256][256] bf16
    const float* __restrict__ bp,    // [256]
    const short* __restrict__ opart, // [KSPLIT][BH][T][64] bf16
    const float* __restrict__ lp,    // [KSPLIT][BH][T]
    const float* __restrict__ x,     // [B][C][T] fp32 residual
    float* __restrict__ out)         // [B][C][T] fp32
{
    const int b  = blockIdx.z;
    const int t0 = blockIdx.x * 64;
    const int o0 = blockIdx.y * 64;

    __shared__ short sm[8192];       // A 8x512 + B 8x512 shorts (16 KiB)
    short* Ab = sm;
    short* Bb = sm + 4096;

    const int tid = threadIdx.x, lane = tid & 63, wave = tid >> 6;
    const int col = lane & 15, quad = lane >> 4;

    const int trow = t0 + 16*wave + col;
    float rl4[NH];
    #pragma unroll
    for (int hh = 0; hh < NH; hh++) {
        float ls = 0.f;
        #pragma unroll
        for (int ks = 0; ks < KSPLIT; ks++)
            ls += lp[((size_t)(ks*BH) + b*NH + hh) * T + trow];
        rl4[hh] = 1.0f / ls;
    }

    f32x4 acc[4];
    #pragma unroll
    for (int g = 0; g < 4; g++) { acc[g][0]=0.f; acc[g][1]=0.f; acc[g][2]=0.f; acc[g][3]=0.f; }

    for (int k0 = 0; k0 < C; k0 += 64) {
        __syncthreads();
        #pragma unroll
        for (int hh = 0; hh < 2; hh++) {
            gll16(wp + (size_t)(o0 + 16*wave + col) * C + k0 + hh*32 + quad*8,
                  Ab + (hh*4 + wave) * 512);
            const int chg = k0 + hh*32 + quad*8;       // global channel
            const int hd = chg >> 6, chin = chg & 63;  // hd is wave-uniform
            const short* ob = opart + (((size_t)(b*NH + hd)) * T + trow) * 64 + chin;
            float a8[8] = {0.f,0.f,0.f,0.f,0.f,0.f,0.f,0.f};
            #pragma unroll
            for (int ks = 0; ks < KSPLIT; ks++) {
                bfv8 v = *(const bfv8*)(ob + (size_t)ks * BH * T * 64);
                #pragma unroll
                for (int u = 0; u < 8; u++) a8[u] += bf2f(v[u]);
            }
            const float rl = rl4[hd];
            bfv8 pk;
            #pragma unroll
            for (int u = 0; u < 8; u++) pk[u] = f2bf(a8[u] * rl);
            *(bfv8*)(Bb + (hh*4 + wave) * 512 + lane*8) = pk;
        }
        __syncthreads();
        #pragma unroll
        for (int hh = 0; hh < 2; hh++) {
            bfv8 af = *(const bfv8*)(Ab + (hh*4 + wave) * 512 + lane*8);
            #pragma unroll
            for (int g = 0; g < 4; g++) {
                bfv8 bf = *(const bfv8*)(Bb + (hh*4 + g) * 512 + lane*8);
                acc[g] = __builtin_amdgcn_mfma_f32_16x16x32_bf16(af, bf, acc[g], 0, 0, 0);
            }
        }
    }

    const int olocal = 16*wave + quad*4;
    #pragma unroll
    for (int r = 0; r < 4; r++) {
        const int o = o0 + olocal + r;
        const float bias = bp[o];
        const size_t rowoff = ((size_t)b * C + o) * T;
        #pragma unroll
        for (int g = 0; g < 4; g++) {
            const size_t idx = rowoff + t0 + 16*g + col;
            out[idx] = acc[g][r] + bias + x[idx];
        }
    }
}

// ---------------------------------------------------------------------------
extern "C" void kernel_launch(void* const* d_in, const int* in_sizes, int n_in,
                              void* d_out, int out_size, void* d_ws, size_t ws_size,
                              hipStream_t stream) {
    (void)in_sizes; (void)n_in; (void)out_size; (void)ws_size;
    const float* x        = (const float*)d_in[0];
    const float* gn_scale = (const float*)d_in[1];
    const float* gn_bias  = (const float*)d_in[2];
    const float* w_qkv    = (const float*)d_in[3];
    const float* b_qkv    = (const float*)d_in[4];
    const float* w_proj   = (const float*)d_in[5];
    const float* b_proj   = (const float*)d_in[6];
    float* out = (float*)d_out;

    short* ws    = (short*)d_ws;
    short* qb    = ws;                                  // [BH][T][64]
    short* kb    = qb  + (size_t)BH * T * 64;
    short* vb    = kb  + (size_t)BH * T * 64;
    short* xnT   = vb  + (size_t)BH * T * 64;           // [B][T][C]
    short* wqb   = xnT + (size_t)BATCH * T * C;
    short* wpb   = wqb + 768 * 256;
    short* opart = wpb + 256 * 256;                     // [4][BH][T][64] bf16
    float* lp    = (float*)(opart + (size_t)KSPLIT * BH * T * 64);  // [4][BH][T]
    float* gnp   = lp + (size_t)KSPLIT * BH * T;        // [64][4][2]

    prep_w<<<dim3(256), 256, 0, stream>>>(w_qkv, w_proj, wqb, wpb);
    gn_stats<<<dim3(BATCH * G, 4), 256, 0, stream>>>(x, gnp);
    gn_norm<<<dim3(BATCH * G, 4), 256, 0, stream>>>(x, gn_scale, gn_bias, gnp, xnT);
    gemm_qkv<<<dim3(T/64, 12, BATCH), 256, 0, stream>>>(wqb, b_qkv, xnT, qb, kb, vb);
    attn_kernel<<<dim3(T/128, BH, KSPLIT), 512, 0, stream>>>(qb, kb, vb, opart, lp);
    gemm_proj<<<dim3(T/64, 4, BATCH), 256, 0, stream>>>(wpb, b_proj, opart, lp, x, out);
}

// Round 4
// 152.372 us; speedup vs baseline: 1.0371x; 1.0371x over previous
//
#include <hip/hip_runtime.h>
#include <math.h>

#define T 4096
#define C 256
#define BATCH 2
#define NH 4
#define G 32
#define CPG 8
#define EPS 1e-5f
#define LOG2E 1.4426950408889634f
// Reference applies scale=ch^-0.25 to q AND k -> logit = (q.k)/8. Fold /8 and
// log2e (exp2-domain softmax) into Q once.
#define QSCALE (0.125f * LOG2E)
#define KSPLIT 4
#define KRANGE (T / KSPLIT)
#define BH (BATCH * NH)

typedef __attribute__((ext_vector_type(8))) short bfv8;
typedef __attribute__((ext_vector_type(4))) short bfv4;
typedef __attribute__((ext_vector_type(4))) float f32x4;
typedef __attribute__((ext_vector_type(16))) float f32x16;

static __device__ __forceinline__ short f2bf(float f) {
    union { float f; unsigned u; } v; v.f = f;
    return (short)((v.u + 0x7FFFu + ((v.u >> 16) & 1u)) >> 16);
}
static __device__ __forceinline__ short f2bf_fast(float f) {  // RN w/o tie-to-even
    union { float f; unsigned u; } v; v.f = f;
    return (short)((v.u + 0x8000u) >> 16);
}
static __device__ __forceinline__ float bf2f(short s) {
    union { float f; unsigned u; } v; v.u = ((unsigned)(unsigned short)s) << 16;
    return v.f;
}

#if __has_builtin(__builtin_amdgcn_exp2f)
#define EXP2(x) __builtin_amdgcn_exp2f(x)
#else
#define EXP2(x) exp2f(x)
#endif

#define AS1 __attribute__((address_space(1)))
#define AS3 __attribute__((address_space(3)))
static __device__ __forceinline__ void gll16(const void* g, void* l) {
    __builtin_amdgcn_global_load_lds((const AS1 void*)g, (AS3 void*)l, 16, 0, 0);
}

// ---------------------------------------------------------------------------
// Weight prep: fp32 -> bf16 for w_qkv [768,256] and w_proj [256,256]
// ---------------------------------------------------------------------------
__global__ __launch_bounds__(256) void prep_w(const float* __restrict__ wq,
                                              const float* __restrict__ wp,
                                              short* __restrict__ wqb,
                                              short* __restrict__ wpb) {
    int i = blockIdx.x * 256 + threadIdx.x;   // float4 index
    const int NQ = 768 * 256 / 4;
    float4 v; short* dst;
    if (i < NQ) { v = ((const float4*)wq)[i]; dst = wqb + i * 4; }
    else        { int j = i - NQ; v = ((const float4*)wp)[j]; dst = wpb + j * 4; }
    bfv4 o = { f2bf(v.x), f2bf(v.y), f2bf(v.z), f2bf(v.w) };
    *(bfv4*)dst = o;
}

// ---------------------------------------------------------------------------
// GroupNorm stats pass: grid (B*G, 4 t-splits), 256 thr.
// ---------------------------------------------------------------------------
__global__ __launch_bounds__(256) void gn_stats(const float* __restrict__ x,
                                                float* __restrict__ gnp) {
    const int blk = blockIdx.x;            // b*G+g
    const int ts  = blockIdx.y;            // 0..3
    const int b = blk / G, g = blk % G;
    const float* xp = x + ((size_t)b * C + g * CPG) * T + ts * 1024;

    const int tid = threadIdx.x;
    float s = 0.f, ss = 0.f;
    #pragma unroll
    for (int u = 0; u < CPG; u++) {
        float4 v = ((const float4*)(xp + (size_t)u * T))[tid];
        s  += v.x + v.y + v.z + v.w;
        ss += v.x*v.x + v.y*v.y + v.z*v.z + v.w*v.w;
    }
    __shared__ float rs[256], rss[256];
    rs[tid] = s; rss[tid] = ss;
    __syncthreads();
    for (int off = 128; off > 0; off >>= 1) {
        if (tid < off) { rs[tid] += rs[tid+off]; rss[tid] += rss[tid+off]; }
        __syncthreads();
    }
    if (tid == 0) {
        gnp[(blk * 4 + ts) * 2 + 0] = rs[0];
        gnp[(blk * 4 + ts) * 2 + 1] = rss[0];
    }
}

// ---------------------------------------------------------------------------
// GroupNorm normalize pass: grid (B*G, 4 t-splits), 256 thr -> bf16 xnT[b][t][c]
// ---------------------------------------------------------------------------
__global__ __launch_bounds__(256) void gn_norm(const float* __restrict__ x,
                                               const float* __restrict__ scale,
                                               const float* __restrict__ bias,
                                               const float* __restrict__ gnp,
                                               short* __restrict__ xnT) {
    const int blk = blockIdx.x;            // b*G+g
    const int ts  = blockIdx.y;            // 0..3
    const int b = blk / G, g = blk % G;
    const int c0 = g * CPG;
    const float* xp = x + ((size_t)b * C + c0) * T;

    float s = 0.f, ss = 0.f;
    #pragma unroll
    for (int i = 0; i < 4; i++) {
        s  += gnp[(blk * 4 + i) * 2 + 0];
        ss += gnp[(blk * 4 + i) * 2 + 1];
    }
    const float inv_n = 1.0f / (CPG * T);
    const float mu  = s * inv_n;
    const float var = ss * inv_n - mu * mu;
    const float rstd = rsqrtf(var + EPS);

    float sc[CPG], bi[CPG];
    #pragma unroll
    for (int u = 0; u < CPG; u++) {
        sc[u] = scale[c0+u] * rstd;
        bi[u] = bias[c0+u] - mu * sc[u];
    }

    const int t = ts * 1024 + threadIdx.x * 4;
    float vv[CPG][4];
    #pragma unroll
    for (int u = 0; u < CPG; u++) {
        float4 v = *(const float4*)&xp[(size_t)u * T + t];
        vv[u][0] = v.x * sc[u] + bi[u];
        vv[u][1] = v.y * sc[u] + bi[u];
        vv[u][2] = v.z * sc[u] + bi[u];
        vv[u][3] = v.w * sc[u] + bi[u];
    }
    #pragma unroll
    for (int j = 0; j < 4; j++) {
        bfv8 w = { f2bf(vv[0][j]), f2bf(vv[1][j]), f2bf(vv[2][j]), f2bf(vv[3][j]),
                   f2bf(vv[4][j]), f2bf(vv[5][j]), f2bf(vv[6][j]), f2bf(vv[7][j]) };
        *(bfv8*)&xnT[((size_t)b * T + t + j) * C + c0] = w;
    }
}

// ---------------------------------------------------------------------------
// qkv GEMM (bf16 MFMA, BK=64 — R9/R11/R13): grid (T/64, 12, BATCH), 256 thr.
// ---------------------------------------------------------------------------
__global__ __launch_bounds__(256) void gemm_qkv(
    const short* __restrict__ wq,    // [768][256] bf16
    const float* __restrict__ bq,    // [768]
    const short* __restrict__ xnT,   // [B][T][C] bf16
    short* __restrict__ qb, short* __restrict__ kb, short* __restrict__ vb)
{
    const int b  = blockIdx.z;
    const int t0 = blockIdx.x * 64;
    const int ot = blockIdx.y;
    const int h = ot / 3, part = ot % 3;
    const int o0 = ot * 64;

    __shared__ short sm[8192];       // A 8x512 + B 8x512 shorts (16 KiB)
    short* Ab = sm;
    short* Bb = sm + 4096;

    const int tid = threadIdx.x, lane = tid & 63, wave = tid >> 6;
    const int col = lane & 15, quad = lane >> 4;
    const short* xb = xnT + (size_t)b * T * C;

    f32x4 acc[4];
    #pragma unroll
    for (int g = 0; g < 4; g++) { acc[g][0]=0.f; acc[g][1]=0.f; acc[g][2]=0.f; acc[g][3]=0.f; }

    for (int k0 = 0; k0 < C; k0 += 64) {
        __syncthreads();
        #pragma unroll
        for (int hh = 0; hh < 2; hh++) {
            gll16(wq + (size_t)(o0 + 16*wave + col) * C + k0 + hh*32 + quad*8,
                  Ab + (hh*4 + wave) * 512);
            gll16(xb + (size_t)(t0 + 16*wave + col) * C + k0 + hh*32 + quad*8,
                  Bb + (hh*4 + wave) * 512);
        }
        __syncthreads();
        #pragma unroll
        for (int hh = 0; hh < 2; hh++) {
            bfv8 af = *(const bfv8*)(Ab + (hh*4 + wave) * 512 + lane*8);
            #pragma unroll
            for (int g = 0; g < 4; g++) {
                bfv8 bf = *(const bfv8*)(Bb + (hh*4 + g) * 512 + lane*8);
                acc[g] = __builtin_amdgcn_mfma_f32_16x16x32_bf16(af, bf, acc[g], 0, 0, 0);
            }
        }
    }

    const int olocal = 16*wave + quad*4;
    float bias_r[4];
    #pragma unroll
    for (int r = 0; r < 4; r++) bias_r[r] = bq[o0 + olocal + r];
    const size_t hd = (size_t)(b * NH + h);

    if (part < 2) {
        short* dst = (part == 0 ? qb : kb) + hd * T * 64;
        const float sc = (part == 0) ? QSCALE : 1.0f;
        #pragma unroll
        for (int g = 0; g < 4; g++) {
            int t = t0 + 16*g + col;
            bfv4 w = { f2bf((acc[g][0] + bias_r[0]) * sc),
                       f2bf((acc[g][1] + bias_r[1]) * sc),
                       f2bf((acc[g][2] + bias_r[2]) * sc),
                       f2bf((acc[g][3] + bias_r[3]) * sc) };
            *(bfv4*)&dst[(size_t)t * 64 + olocal] = w;
        }
    } else {
        short* dst = vb + hd * 64 * T;
        #pragma unroll
        for (int g = 0; g < 4; g++)
            #pragma unroll
            for (int r = 0; r < 4; r++)
                dst[(size_t)(olocal + r) * T + t0 + 16*g + col] =
                    f2bf(acc[g][r] + bias_r[r]);
    }
}

// ---------------------------------------------------------------------------
// Flash attention v11: v8's partition (256 q/block, 8 waves, dbuf staging,
// grid (16,BH,KSPLIT)=512 blocks=2/CU) with the whole compute moved to
// 32x32x16 MFMA. R0-R2 established: MFMA-pipe busy was 21.2us of the 49.6us
// wall, 2/3 of it the half-rate 16x16x16 PV; issue slots and occupancy are
// NOT the limiter. 32x32x16 gives: full-rate K=16 PV with the P-fragment
// built IN-LANE (no permlane: S^T 32x32 output keys (r&3)+8*(r>>2)+4hi match
// PV B-slots under key-perm kappa(kc,hi,j)=16kc+4hi+(j&3)+8*(j>>2), i.e.
// B-frag(kc) = pack(sacc[8*(kc&1)+j])), kappa applied to V via its LDS read
// addresses. 16 MFMA32/wave-iter vs v8's 16 MFMA32-equiv + 32 MFMA16.
// K/V LDS tiles are XOR-chunk-swizzled (T2) with PRE-SWIZZLED global source
// (m173: gll16 dest linear, src chunk ^= row&7) so all K reads (b128) and
// V reads (b64) are bank-balanced. Q/K row layout [64ch]; V rows [64keys].
// R3 NOTE: previous submission died to a container-acquisition failure (no
// bench data); full bounds/layout audit found no fault — resubmitting as-is.
// ---------------------------------------------------------------------------
__global__ __launch_bounds__(512, 4) void attn_kernel(
    const short* __restrict__ qb,    // [BH][T][64] (pre-scaled by QSCALE)
    const short* __restrict__ kb,    // [BH][T][64]
    const short* __restrict__ vb,    // [BH][64][T]
    short* __restrict__ opart,       // [KSPLIT][BH][T][64] unnormalized O, bf16
    float* __restrict__ lp)          // [KSPLIT][BH][T]
{
    __shared__ short smem[16384];    // 2 x (K 8KB + V 8KB) = 32 KiB
    const int bh = blockIdx.y;
    const int ks = blockIdx.z;
    const int t0 = blockIdx.x * 256;
    const int k0base = ks * KRANGE;
    const short* kbh = kb + (size_t)bh * T * 64;
    const short* vbh = vb + (size_t)bh * 64 * T;

    const int tid  = threadIdx.x;
    const int lane = tid & 63;
    const int wave = tid >> 6;       // 0..7
    const int klow = lane & 31;      // m-index (key / ch) and n-index (query)
    const int hi   = lane >> 5;
    const int swz  = klow & 7;       // XOR-swizzle key for this lane's rows

    // Q B-frags: step s covers ch 16s..16s+15; slot (hi,j) -> ch 16s+8hi+j
    const int q = t0 + wave*32 + klow;
    const short* qrow = qb + (size_t)bh * T * 64 + (size_t)q * 64;
    bfv8 qf[4];
    #pragma unroll
    for (int s = 0; s < 4; s++) qf[s] = *(const bfv8*)(qrow + s*16 + hi*8);

    // O^T accumulators: tile c -> ch = 32c + (r&3)+8*(r>>2)+4hi, query = klow
    f32x16 oacc[2];
    #pragma unroll
    for (int c = 0; c < 2; c++)
        #pragma unroll
        for (int r = 0; r < 16; r++) oacc[c][r] = 0.f;
    float lsum = 0.f;

    // Staging: 512 lanes cover 64 rows x 8 chunks (16B each). LDS dest is
    // linear (gll16); global source chunk index is XOR'd with row&7 so the
    // LDS tile is chunk-swizzled: LDS[row][chunk] = row[8*(chunk^(row&7))..].
    const int srow = wave*8 + (lane >> 3);    // key (K tile) / ch (V tile)
    const int schunk = lane & 7;
    #define STAGE_KV(buf, s0)                                                   \
        {                                                                       \
            short* kB = smem + (buf) * 8192 + wave * 512;                       \
            gll16(kbh + (size_t)((s0) + srow) * 64 + ((schunk ^ (srow&7))<<3),  \
                  kB);                                                          \
            gll16(vbh + (size_t)srow * T + (s0) + ((schunk ^ (srow&7))<<3),     \
                  kB + 4096);                                                   \
        }

    STAGE_KV(0, k0base)

    for (int it = 0; it < KRANGE/64; it++) {
        __syncthreads();                        // staged tile visible
        if (it + 1 < KRANGE/64) STAGE_KV((it+1) & 1, k0base + (it+1)*64)

        const short* kvb = smem + (it & 1) * 8192;
        const short* kl = kvb + klow*64;                 // K row for this lane
        const short* vl = kvb + 4096 + klow*64 + 4*hi;   // V row base (+key 4hi)

        // S^T per key-tile kt (keys 32kt..32kt+31):
        //   A = K[32kt+klow][16s+8hi+j] (swizzled b128), B = qf[s]
        //   D: key (r&3)+8*(r>>2)+4hi+32kt, query klow
        // then exp2 -> pack B-frags pf[kt][u] = {p[8u+j]} (keys match kappa).
        bfv8 pf[2][2];
        #pragma unroll
        for (int kt = 0; kt < 2; kt++) {
            f32x16 sacc;
            #pragma unroll
            for (int r = 0; r < 16; r++) sacc[r] = 0.f;
            #pragma unroll
            for (int s = 0; s < 4; s++) {
                bfv8 kf = *(const bfv8*)(kl + kt*2048 + (((2*s+hi) ^ swz) << 3));
                sacc = __builtin_amdgcn_mfma_f32_32x32x16_bf16(kf, qf[s], sacc, 0, 0, 0);
            }
            #pragma unroll
            for (int u = 0; u < 2; u++) {
                bfv8 pk;
                #pragma unroll
                for (int j = 0; j < 8; j++) {
                    float p = EXP2(sacc[u*8 + j]);
                    lsum += p;
                    pk[j] = f2bf_fast(p);
                }
                pf[kt][u] = pk;
            }
        }

        // PV: chunk kc covers keys kappa(kc,hi,j)=16kc+4hi+(j&3)+8*(j>>2).
        //   A = V[32c+klow][kappa] = 2x b64 at swizzled chunks 2kc, 2kc+1
        //   B = pf[kc>>1][kc&1]
        #pragma unroll
        for (int kc = 0; kc < 4; kc++) {
            #pragma unroll
            for (int c = 0; c < 2; c++) {
                bfv4 v0 = *(const bfv4*)(vl + c*2048 + (((2*kc)   ^ swz) << 3));
                bfv4 v1 = *(const bfv4*)(vl + c*2048 + (((2*kc+1) ^ swz) << 3));
                bfv8 vf = { v0[0], v0[1], v0[2], v0[3],
                            v1[0], v1[1], v1[2], v1[3] };
                oacc[c] = __builtin_amdgcn_mfma_f32_32x32x16_bf16(
                              vf, pf[kc>>1][kc&1], oacc[c], 0, 0, 0);
            }
        }
    }

    // l: lane holds 32 of the 64 keys (its hi half) for query klow
    lsum += __shfl_xor(lsum, 32);

    // epilogue: lane owns t-row (t0+wave*32+klow); ch = 32c + 8u + 4hi + i
    const size_t rowbase = (size_t)(ks*BH + bh) * T + t0 + wave*32;
    short* opb = opart + (rowbase + klow) * 64;
    #pragma unroll
    for (int c = 0; c < 2; c++)
        #pragma unroll
        for (int u = 0; u < 4; u++) {
            bfv4 w = { f2bf(oacc[c][4*u+0]), f2bf(oacc[c][4*u+1]),
                       f2bf(oacc[c][4*u+2]), f2bf(oacc[c][4*u+3]) };
            *(bfv4*)(opb + c*32 + u*8 + hi*4) = w;
        }
    if (hi == 0) {
        lp[rowbase + klow] = lsum;
    }
}

// ---------------------------------------------------------------------------
// proj GEMM (bf16 MFMA, BK=64) with fused combine (R9/R11/R13): B-operand
// built from opart (sum KSPLIT partials x per-head rl). + bias + fp32 resid.
// grid (T/64, 4, BATCH).
// ---------------------------------------------------------------------------
__global__ __launch_bounds__(256) void gemm_proj(
    const short* __restrict__ wp,    // [256][256] bf16
    const float* __restrict__ bp,    // [256]
    const short* __restrict__ opart, // [KSPLIT][BH][T][64] bf16
    const float* __restrict__ lp,    // [KSPLIT][BH][T]
    const float* __restrict__ x,     // [B][C][T] fp32 residual
    float* __restrict__ out)         // [B][C][T] fp32
{
    const int b  = blockIdx.z;
    const int t0 = blockIdx.x * 64;
    const int o0 = blockIdx.y * 64;

    __shared__ short sm[8192];       // A 8x512 + B 8x512 shorts (16 KiB)
    short* Ab = sm;
    short* Bb = sm + 4096;

    const int tid = threadIdx.x, lane = tid & 63, wave = tid >> 6;
    const int col = lane & 15, quad = lane >> 4;

    const int trow = t0 + 16*wave + col;
    float rl4[NH];
    #pragma unroll
    for (int hh = 0; hh < NH; hh++) {
        float ls = 0.f;
        #pragma unroll
        for (int ks = 0; ks < KSPLIT; ks++)
            ls += lp[((size_t)(ks*BH) + b*NH + hh) * T + trow];
        rl4[hh] = 1.0f / ls;
    }

    f32x4 acc[4];
    #pragma unroll
    for (int g = 0; g < 4; g++) { acc[g][0]=0.f; acc[g][1]=0.f; acc[g][2]=0.f; acc[g][3]=0.f; }

    for (int k0 = 0; k0 < C; k0 += 64) {
        __syncthreads();
        #pragma unroll
        for (int hh = 0; hh < 2; hh++) {
            gll16(wp + (size_t)(o0 + 16*wave + col) * C + k0 + hh*32 + quad*8,
                  Ab + (hh*4 + wave) * 512);
            const int chg = k0 + hh*32 + quad*8;       // global channel
            const int hd = chg >> 6, chin = chg & 63;  // hd is wave-uniform
            const short* ob = opart + (((size_t)(b*NH + hd)) * T + trow) * 64 + chin;
            float a8[8] = {0.f,0.f,0.f,0.f,0.f,0.f,0.f,0.f};
            #pragma unroll
            for (int ks = 0; ks < KSPLIT; ks++) {
                bfv8 v = *(const bfv8*)(ob + (size_t)ks * BH * T * 64);
                #pragma unroll
                for (int u = 0; u < 8; u++) a8[u] += bf2f(v[u]);
            }
            const float rl = rl4[hd];
            bfv8 pk;
            #pragma unroll
            for (int u = 0; u < 8; u++) pk[u] = f2bf(a8[u] * rl);
            *(bfv8*)(Bb + (hh*4 + wave) * 512 + lane*8) = pk;
        }
        __syncthreads();
        #pragma unroll
        for (int hh = 0; hh < 2; hh++) {
            bfv8 af = *(const bfv8*)(Ab + (hh*4 + wave) * 512 + lane*8);
            #pragma unroll
            for (int g = 0; g < 4; g++) {
                bfv8 bf = *(const bfv8*)(Bb + (hh*4 + g) * 512 + lane*8);
                acc[g] = __builtin_amdgcn_mfma_f32_16x16x32_bf16(af, bf, acc[g], 0, 0, 0);
            }
        }
    }

    const int olocal = 16*wave + quad*4;
    #pragma unroll
    for (int r = 0; r < 4; r++) {
        const int o = o0 + olocal + r;
        const float bias = bp[o];
        const size_t rowoff = ((size_t)b * C + o) * T;
        #pragma unroll
        for (int g = 0; g < 4; g++) {
            const size_t idx = rowoff + t0 + 16*g + col;
            out[idx] = acc[g][r] + bias + x[idx];
        }
    }
}

// ---------------------------------------------------------------------------
extern "C" void kernel_launch(void* const* d_in, const int* in_sizes, int n_in,
                              void* d_out, int out_size, void* d_ws, size_t ws_size,
                              hipStream_t stream) {
    (void)in_sizes; (void)n_in; (void)out_size; (void)ws_size;
    const float* x        = (const float*)d_in[0];
    const float* gn_scale = (const float*)d_in[1];
    const float* gn_bias  = (const float*)d_in[2];
    const float* w_qkv    = (const float*)d_in[3];
    const float* b_qkv    = (const float*)d_in[4];
    const float* w_proj   = (const float*)d_in[5];
    const float* b_proj   = (const float*)d_in[6];
    float* out = (float*)d_out;

    short* ws    = (short*)d_ws;
    short* qb    = ws;                                  // [BH][T][64]
    short* kb    = qb  + (size_t)BH * T * 64;
    short* vb    = kb  + (size_t)BH * T * 64;
    short* xnT   = vb  + (size_t)BH * T * 64;           // [B][T][C]
    short* wqb   = xnT + (size_t)BATCH * T * C;
    short* wpb   = wqb + 768 * 256;
    short* opart = wpb + 256 * 256;                     // [4][BH][T][64] bf16
    float* lp    = (float*)(opart + (size_t)KSPLIT * BH * T * 64);  // [4][BH][T]
    float* gnp   = lp + (size_t)KSPLIT * BH * T;        // [64][4][2]

    prep_w<<<dim3(256), 256, 0, stream>>>(w_qkv, w_proj, wqb, wpb);
    gn_stats<<<dim3(BATCH * G, 4), 256, 0, stream>>>(x, gnp);
    gn_norm<<<dim3(BATCH * G, 4), 256, 0, stream>>>(x, gn_scale, gn_bias, gnp, xnT);
    gemm_qkv<<<dim3(T/64, 12, BATCH), 256, 0, stream>>>(wqb, b_qkv, xnT, qb, kb, vb);
    attn_kernel<<<dim3(T/256, BH, KSPLIT), 512, 0, stream>>>(qb, kb, vb, opart, lp);
    gemm_proj<<<dim3(T/64, 4, BATCH), 256, 0, stream>>>(wpb, b_proj, opart, lp, x, out);
}

// Round 5
// 150.409 us; speedup vs baseline: 1.0506x; 1.0131x over previous
//
#include <hip/hip_runtime.h>
#include <math.h>

#define T 4096
#define C 256
#define BATCH 2
#define NH 4
#define G 32
#define CPG 8
#define EPS 1e-5f
#define LOG2E 1.4426950408889634f
// Reference applies scale=ch^-0.25 to q AND k -> logit = (q.k)/8. Fold /8 and
// log2e (exp2-domain softmax) into Q once.
#define QSCALE (0.125f * LOG2E)
#define KSPLIT 4
#define KRANGE (T / KSPLIT)
#define KTILE 128
#define NIT (KRANGE / KTILE)
#define BH (BATCH * NH)

typedef __attribute__((ext_vector_type(8))) short bfv8;
typedef __attribute__((ext_vector_type(4))) short bfv4;
typedef __attribute__((ext_vector_type(4))) float f32x4;
typedef __attribute__((ext_vector_type(2))) float f32x2;
typedef __attribute__((ext_vector_type(16))) float f32x16;

static __device__ __forceinline__ short f2bf(float f) {
    union { float f; unsigned u; } v; v.f = f;
    return (short)((v.u + 0x7FFFu + ((v.u >> 16) & 1u)) >> 16);
}
static __device__ __forceinline__ float bf2f(short s) {
    union { float f; unsigned u; } v; v.u = ((unsigned)(unsigned short)s) << 16;
    return v.f;
}

#if __has_builtin(__builtin_amdgcn_exp2f)
#define EXP2(x) __builtin_amdgcn_exp2f(x)
#else
#define EXP2(x) exp2f(x)
#endif

#define AS1 __attribute__((address_space(1)))
#define AS3 __attribute__((address_space(3)))
static __device__ __forceinline__ void gll16(const void* g, void* l) {
    __builtin_amdgcn_global_load_lds((const AS1 void*)g, (AS3 void*)l, 16, 0, 0);
}

// ---------------------------------------------------------------------------
// Merged: weight prep (blocks 0..255) + GroupNorm stats (blocks 256..511).
// Independent ops sharing one launch (R4: ~104us of the 152 sits outside
// attn; launch-gap reduction is near-free).
// ---------------------------------------------------------------------------
__global__ __launch_bounds__(256) void prep_stats(
    const float* __restrict__ wq, const float* __restrict__ wp,
    short* __restrict__ wqb, short* __restrict__ wpb,
    const float* __restrict__ x, float* __restrict__ gnp)
{
    __shared__ float rs[256], rss[256];
    const int bid = blockIdx.x;
    const int tid = threadIdx.x;
    if (bid < 256) {
        int i = bid * 256 + tid;   // float4 index
        const int NQ = 768 * 256 / 4;
        float4 v; short* dst;
        if (i < NQ) { v = ((const float4*)wq)[i]; dst = wqb + i * 4; }
        else        { int j = i - NQ; v = ((const float4*)wp)[j]; dst = wpb + j * 4; }
        bfv4 o = { f2bf(v.x), f2bf(v.y), f2bf(v.z), f2bf(v.w) };
        *(bfv4*)dst = o;
        return;
    }
    const int blk = (bid - 256) >> 2;      // b*G+g
    const int ts  = (bid - 256) & 3;       // 0..3
    const int b = blk / G, g = blk % G;
    const float* xp = x + ((size_t)b * C + g * CPG) * T + ts * 1024;

    float s = 0.f, ss = 0.f;
    #pragma unroll
    for (int u = 0; u < CPG; u++) {
        float4 v = ((const float4*)(xp + (size_t)u * T))[tid];
        s  += v.x + v.y + v.z + v.w;
        ss += v.x*v.x + v.y*v.y + v.z*v.z + v.w*v.w;
    }
    rs[tid] = s; rss[tid] = ss;
    __syncthreads();
    for (int off = 128; off > 0; off >>= 1) {
        if (tid < off) { rs[tid] += rs[tid+off]; rss[tid] += rss[tid+off]; }
        __syncthreads();
    }
    if (tid == 0) {
        gnp[(blk * 4 + ts) * 2 + 0] = rs[0];
        gnp[(blk * 4 + ts) * 2 + 1] = rss[0];
    }
}

// ---------------------------------------------------------------------------
// GroupNorm normalize pass: grid (B*G, 4 t-splits), 256 thr -> bf16 xnT[b][t][c]
// ---------------------------------------------------------------------------
__global__ __launch_bounds__(256) void gn_norm(const float* __restrict__ x,
                                               const float* __restrict__ scale,
                                               const float* __restrict__ bias,
                                               const float* __restrict__ gnp,
                                               short* __restrict__ xnT) {
    const int blk = blockIdx.x;            // b*G+g
    const int ts  = blockIdx.y;            // 0..3
    const int b = blk / G, g = blk % G;
    const int c0 = g * CPG;
    const float* xp = x + ((size_t)b * C + c0) * T;

    float s = 0.f, ss = 0.f;
    #pragma unroll
    for (int i = 0; i < 4; i++) {
        s  += gnp[(blk * 4 + i) * 2 + 0];
        ss += gnp[(blk * 4 + i) * 2 + 1];
    }
    const float inv_n = 1.0f / (CPG * T);
    const float mu  = s * inv_n;
    const float var = ss * inv_n - mu * mu;
    const float rstd = rsqrtf(var + EPS);

    float sc[CPG], bi[CPG];
    #pragma unroll
    for (int u = 0; u < CPG; u++) {
        sc[u] = scale[c0+u] * rstd;
        bi[u] = bias[c0+u] - mu * sc[u];
    }

    const int t = ts * 1024 + threadIdx.x * 4;
    float vv[CPG][4];
    #pragma unroll
    for (int u = 0; u < CPG; u++) {
        float4 v = *(const float4*)&xp[(size_t)u * T + t];
        vv[u][0] = v.x * sc[u] + bi[u];
        vv[u][1] = v.y * sc[u] + bi[u];
        vv[u][2] = v.z * sc[u] + bi[u];
        vv[u][3] = v.w * sc[u] + bi[u];
    }
    #pragma unroll
    for (int j = 0; j < 4; j++) {
        bfv8 w = { f2bf(vv[0][j]), f2bf(vv[1][j]), f2bf(vv[2][j]), f2bf(vv[3][j]),
                   f2bf(vv[4][j]), f2bf(vv[5][j]), f2bf(vv[6][j]), f2bf(vv[7][j]) };
        *(bfv8*)&xnT[((size_t)b * T + t + j) * C + c0] = w;
    }
}

// ---------------------------------------------------------------------------
// qkv GEMM (bf16 MFMA, BK=64 — R9/R11/R13): grid (T/64, 12, BATCH), 256 thr.
// ---------------------------------------------------------------------------
__global__ __launch_bounds__(256) void gemm_qkv(
    const short* __restrict__ wq,    // [768][256] bf16
    const float* __restrict__ bq,    // [768]
    const short* __restrict__ xnT,   // [B][T][C] bf16
    short* __restrict__ qb, short* __restrict__ kb, short* __restrict__ vb)
{
    const int b  = blockIdx.z;
    const int t0 = blockIdx.x * 64;
    const int ot = blockIdx.y;
    const int h = ot / 3, part = ot % 3;
    const int o0 = ot * 64;

    __shared__ short sm[8192];       // A 8x512 + B 8x512 shorts (16 KiB)
    short* Ab = sm;
    short* Bb = sm + 4096;

    const int tid = threadIdx.x, lane = tid & 63, wave = tid >> 6;
    const int col = lane & 15, quad = lane >> 4;
    const short* xb = xnT + (size_t)b * T * C;

    f32x4 acc[4];
    #pragma unroll
    for (int g = 0; g < 4; g++) { acc[g][0]=0.f; acc[g][1]=0.f; acc[g][2]=0.f; acc[g][3]=0.f; }

    for (int k0 = 0; k0 < C; k0 += 64) {
        __syncthreads();
        #pragma unroll
        for (int hh = 0; hh < 2; hh++) {
            gll16(wq + (size_t)(o0 + 16*wave + col) * C + k0 + hh*32 + quad*8,
                  Ab + (hh*4 + wave) * 512);
            gll16(xb + (size_t)(t0 + 16*wave + col) * C + k0 + hh*32 + quad*8,
                  Bb + (hh*4 + wave) * 512);
        }
        __syncthreads();
        #pragma unroll
        for (int hh = 0; hh < 2; hh++) {
            bfv8 af = *(const bfv8*)(Ab + (hh*4 + wave) * 512 + lane*8);
            #pragma unroll
            for (int g = 0; g < 4; g++) {
                bfv8 bf = *(const bfv8*)(Bb + (hh*4 + g) * 512 + lane*8);
                acc[g] = __builtin_amdgcn_mfma_f32_16x16x32_bf16(af, bf, acc[g], 0, 0, 0);
            }
        }
    }

    const int olocal = 16*wave + quad*4;
    float bias_r[4];
    #pragma unroll
    for (int r = 0; r < 4; r++) bias_r[r] = bq[o0 + olocal + r];
    const size_t hd = (size_t)(b * NH + h);

    if (part < 2) {
        short* dst = (part == 0 ? qb : kb) + hd * T * 64;
        const float sc = (part == 0) ? QSCALE : 1.0f;
        #pragma unroll
        for (int g = 0; g < 4; g++) {
            int t = t0 + 16*g + col;
            bfv4 w = { f2bf((acc[g][0] + bias_r[0]) * sc),
                       f2bf((acc[g][1] + bias_r[1]) * sc),
                       f2bf((acc[g][2] + bias_r[2]) * sc),
                       f2bf((acc[g][3] + bias_r[3]) * sc) };
            *(bfv4*)&dst[(size_t)t * 64 + olocal] = w;
        }
    } else {
        short* dst = vb + hd * 64 * T;
        #pragma unroll
        for (int g = 0; g < 4; g++)
            #pragma unroll
            for (int r = 0; r < 4; r++)
                dst[(size_t)(olocal + r) * T + t0 + 16*g + col] =
                    f2bf(acc[g][r] + bias_r[r]);
    }
}

// ---------------------------------------------------------------------------
// Flash attention v12: v11's 32x32x16 structure with (a) KTILE 64->128
// (halves barrier count 16->8; LDS 2x32KB=64KB, still 2 blocks/CU), S^T and
// PV interleaved per 32-key sub-tile to keep P live-range small; (b) P
// packing via v_cvt_pk_bf16_f32 (pairs are register-adjacent in this layout
// -> 1 op replaces ~6 of f2bf+insert; v9 proved the VALU-busy cut); (c)
// lsum accumulated as f32x2 (targets v_pk_add_f32). R4 post-mortem: VALU is
// the top pipe consumer (23.7us busy vs MFMA 13.9us); this attacks VALU +
// barrier-aligned stalls.
// K tile [128 key][64 ch] rows 8x16B chunks, swz key row&7 = klow&7.
// V tile [64 ch][128 key] rows 16x16B chunks, swz key row&15 = klow&15.
// Both staged with pre-swizzled global source (m173), read with same XOR.
// ---------------------------------------------------------------------------
__global__ __launch_bounds__(512, 4) void attn_kernel(
    const short* __restrict__ qb,    // [BH][T][64] (pre-scaled by QSCALE)
    const short* __restrict__ kb,    // [BH][T][64]
    const short* __restrict__ vb,    // [BH][64][T]
    short* __restrict__ opart,       // [KSPLIT][BH][T][64] unnormalized O, bf16
    float* __restrict__ lp)          // [KSPLIT][BH][T]
{
    __shared__ short smem[32768];    // 2 x (K 16KB + V 16KB) = 64 KiB
    const int bh = blockIdx.y;
    const int ks = blockIdx.z;
    const int t0 = blockIdx.x * 256;
    const int k0base = ks * KRANGE;
    const short* kbh = kb + (size_t)bh * T * 64;
    const short* vbh = vb + (size_t)bh * 64 * T;

    const int tid  = threadIdx.x;
    const int lane = tid & 63;
    const int wave = tid >> 6;       // 0..7
    const int klow = lane & 31;      // m-index (key / ch) and n-index (query)
    const int hi   = lane >> 5;
    const int swz  = klow & 7;       // K-tile XOR key (8 chunks/row)
    const int vswz = klow & 15;      // V-tile XOR key (16 chunks/row)

    // Q B-frags: step s covers ch 16s..16s+15; slot (hi,j) -> ch 16s+8hi+j
    const int q = t0 + wave*32 + klow;
    const short* qrow = qb + (size_t)bh * T * 64 + (size_t)q * 64;
    bfv8 qf[4];
    #pragma unroll
    for (int s = 0; s < 4; s++) qf[s] = *(const bfv8*)(qrow + s*16 + hi*8);

    // O^T accumulators: tile c -> ch = 32c + (r&3)+8*(r>>2)+4hi, query = klow
    f32x16 oacc[2];
    #pragma unroll
    for (int c = 0; c < 2; c++)
        #pragma unroll
        for (int r = 0; r < 16; r++) oacc[c][r] = 0.f;
    f32x2 l2 = { 0.f, 0.f };

    // Staging: per buffer, K = 1024 chunks (128 rows x 8), V = 1024 chunks
    // (64 rows x 16). Each wave issues 2 K + 2 V gll16 (lane covers 16B).
    // LDS dest linear; global source chunk XOR'd with row's swizzle key.
    const int lr8  = lane >> 3, lc8  = lane & 7;    // K staging row-sub/chunk
    const int lr16 = lane >> 4, lc16 = lane & 15;   // V staging row-sub/chunk
    #define STAGE_KV(buf, s0)                                                   \
        {                                                                       \
            short* base = smem + (buf) * 16384;                                 \
            const int r0 = (wave*2+0)*8 + lr8;                                  \
            const int r1 = (wave*2+1)*8 + lr8;                                  \
            gll16(kbh + (size_t)((s0) + r0) * 64 + ((lc8 ^ (r0&7))<<3),         \
                  base + (wave*2+0)*512);                                       \
            gll16(kbh + (size_t)((s0) + r1) * 64 + ((lc8 ^ (r1&7))<<3),         \
                  base + (wave*2+1)*512);                                       \
            const int v0r = (wave*2+0)*4 + lr16;                                \
            const int v1r = (wave*2+1)*4 + lr16;                                \
            gll16(vbh + (size_t)v0r * T + (s0) + ((lc16 ^ (v0r&15))<<3),        \
                  base + 8192 + (wave*2+0)*512);                                \
            gll16(vbh + (size_t)v1r * T + (s0) + ((lc16 ^ (v1r&15))<<3),        \
                  base + 8192 + (wave*2+1)*512);                                \
        }

    STAGE_KV(0, k0base)

    for (int it = 0; it < NIT; it++) {
        __syncthreads();                        // staged tile visible
        if (it + 1 < NIT) STAGE_KV((it+1) & 1, k0base + (it+1)*KTILE)

        const short* kvb = smem + (it & 1) * 16384;
        const short* kl = kvb + klow*64;                   // K row for this lane
        const short* vl = kvb + 8192 + klow*128 + 4*hi;    // V row base (+key 4hi)

        // Per 32-key sub-tile kt: S^T -> exp2 -> cvt_pk pack -> PV (kc=2kt+u)
        #pragma unroll
        for (int kt = 0; kt < 4; kt++) {
            f32x16 sacc;
            #pragma unroll
            for (int r = 0; r < 16; r++) sacc[r] = 0.f;
            #pragma unroll
            for (int s = 0; s < 4; s++) {
                bfv8 kf = *(const bfv8*)(kl + kt*2048 + (((2*s+hi) ^ swz) << 3));
                sacc = __builtin_amdgcn_mfma_f32_32x32x16_bf16(kf, qf[s], sacc, 0, 0, 0);
            }
            #pragma unroll
            for (int u = 0; u < 2; u++) {
                float p[8];
                #pragma unroll
                for (int j = 0; j < 8; j++) p[j] = EXP2(sacc[8*u + j]);
                f32x2 pa = { p[0], p[1] }, pb = { p[2], p[3] };
                f32x2 pc = { p[4], p[5] }, pd = { p[6], p[7] };
                l2 += (pa + pb) + (pc + pd);
                union { unsigned w[4]; bfv8 v; } pk_;
                #pragma unroll
                for (int w = 0; w < 4; w++)
                    asm("v_cvt_pk_bf16_f32 %0, %1, %2"
                        : "=v"(pk_.w[w]) : "v"(p[2*w]), "v"(p[2*w+1]));
                const int kc = 2*kt + u;    // keys kappa = 16kc+4hi+(j&3)+8*(j>>2)
                #pragma unroll
                for (int c = 0; c < 2; c++) {
                    bfv4 v0 = *(const bfv4*)(vl + c*4096 + (((2*kc)   ^ vswz) << 3));
                    bfv4 v1 = *(const bfv4*)(vl + c*4096 + (((2*kc+1) ^ vswz) << 3));
                    bfv8 vf = { v0[0], v0[1], v0[2], v0[3],
                                v1[0], v1[1], v1[2], v1[3] };
                    oacc[c] = __builtin_amdgcn_mfma_f32_32x32x16_bf16(
                                  vf, pk_.v, oacc[c], 0, 0, 0);
                }
            }
        }
    }

    // l: lane holds 32 of the 64 keys (its hi half) for query klow
    float lsum = l2[0] + l2[1];
    lsum += __shfl_xor(lsum, 32);

    // epilogue: lane owns t-row (t0+wave*32+klow); ch = 32c + 8u + 4hi + i
    const size_t rowbase = (size_t)(ks*BH + bh) * T + t0 + wave*32;
    short* opb = opart + (rowbase + klow) * 64;
    #pragma unroll
    for (int c = 0; c < 2; c++)
        #pragma unroll
        for (int u = 0; u < 4; u++) {
            bfv4 w = { f2bf(oacc[c][4*u+0]), f2bf(oacc[c][4*u+1]),
                       f2bf(oacc[c][4*u+2]), f2bf(oacc[c][4*u+3]) };
            *(bfv4*)(opb + c*32 + u*8 + hi*4) = w;
        }
    if (hi == 0) {
        lp[rowbase + klow] = lsum;
    }
}

// ---------------------------------------------------------------------------
// proj GEMM (bf16 MFMA, BK=64) with fused combine (R9/R11/R13): B-operand
// built from opart (sum KSPLIT partials x per-head rl). + bias + fp32 resid.
// grid (T/64, 4, BATCH).
// ---------------------------------------------------------------------------
__global__ __launch_bounds__(256) void gemm_proj(
    const short* __restrict__ wp,    // [256][256] bf16
    const float* __restrict__ bp,    // [256]
    const short* __restrict__ opart, // [KSPLIT][BH][T][64] bf16
    const float* __restrict__ lp,    // [KSPLIT][BH][T]
    const float* __restrict__ x,     // [B][C][T] fp32 residual
    float* __restrict__ out)         // [B][C][T] fp32
{
    const int b  = blockIdx.z;
    const int t0 = blockIdx.x * 64;
    const int o0 = blockIdx.y * 64;

    __shared__ short sm[8192];       // A 8x512 + B 8x512 shorts (16 KiB)
    short* Ab = sm;
    short* Bb = sm + 4096;

    const int tid = threadIdx.x, lane = tid & 63, wave = tid >> 6;
    const int col = lane & 15, quad = lane >> 4;

    const int trow = t0 + 16*wave + col;
    float rl4[NH];
    #pragma unroll
    for (int hh = 0; hh < NH; hh++) {
        float ls = 0.f;
        #pragma unroll
        for (int ks = 0; ks < KSPLIT; ks++)
            ls += lp[((size_t)(ks*BH) + b*NH + hh) * T + trow];
        rl4[hh] = 1.0f / ls;
    }

    f32x4 acc[4];
    #pragma unroll
    for (int g = 0; g < 4; g++) { acc[g][0]=0.f; acc[g][1]=0.f; acc[g][2]=0.f; acc[g][3]=0.f; }

    for (int k0 = 0; k0 < C; k0 += 64) {
        __syncthreads();
        #pragma unroll
        for (int hh = 0; hh < 2; hh++) {
            gll16(wp + (size_t)(o0 + 16*wave + col) * C + k0 + hh*32 + quad*8,
                  Ab + (hh*4 + wave) * 512);
            const int chg = k0 + hh*32 + quad*8;       // global channel
            const int hd = chg >> 6, chin = chg & 63;  // hd is wave-uniform
            const short* ob = opart + (((size_t)(b*NH + hd)) * T + trow) * 64 + chin;
            float a8[8] = {0.f,0.f,0.f,0.f,0.f,0.f,0.f,0.f};
            #pragma unroll
            for (int ks = 0; ks < KSPLIT; ks++) {
                bfv8 v = *(const bfv8*)(ob + (size_t)ks * BH * T * 64);
                #pragma unroll
                for (int u = 0; u < 8; u++) a8[u] += bf2f(v[u]);
            }
            const float rl = rl4[hd];
            bfv8 pk;
            #pragma unroll
            for (int u = 0; u < 8; u++) pk[u] = f2bf(a8[u] * rl);
            *(bfv8*)(Bb + (hh*4 + wave) * 512 + lane*8) = pk;
        }
        __syncthreads();
        #pragma unroll
        for (int hh = 0; hh < 2; hh++) {
            bfv8 af = *(const bfv8*)(Ab + (hh*4 + wave) * 512 + lane*8);
            #pragma unroll
            for (int g = 0; g < 4; g++) {
                bfv8 bf = *(const bfv8*)(Bb + (hh*4 + g) * 512 + lane*8);
                acc[g] = __builtin_amdgcn_mfma_f32_16x16x32_bf16(af, bf, acc[g], 0, 0, 0);
            }
        }
    }

    const int olocal = 16*wave + quad*4;
    #pragma unroll
    for (int r = 0; r < 4; r++) {
        const int o = o0 + olocal + r;
        const float bias = bp[o];
        const size_t rowoff = ((size_t)b * C + o) * T;
        #pragma unroll
        for (int g = 0; g < 4; g++) {
            const size_t idx = rowoff + t0 + 16*g + col;
            out[idx] = acc[g][r] + bias + x[idx];
        }
    }
}

// ---------------------------------------------------------------------------
extern "C" void kernel_launch(void* const* d_in, const int* in_sizes, int n_in,
                              void* d_out, int out_size, void* d_ws, size_t ws_size,
                              hipStream_t stream) {
    (void)in_sizes; (void)n_in; (void)out_size; (void)ws_size;
    const float* x        = (const float*)d_in[0];
    const float* gn_scale = (const float*)d_in[1];
    const float* gn_bias  = (const float*)d_in[2];
    const float* w_qkv    = (const float*)d_in[3];
    const float* b_qkv    = (const float*)d_in[4];
    const float* w_proj   = (const float*)d_in[5];
    const float* b_proj   = (const float*)d_in[6];
    float* out = (float*)d_out;

    short* ws    = (short*)d_ws;
    short* qb    = ws;                                  // [BH][T][64]
    short* kb    = qb  + (size_t)BH * T * 64;
    short* vb    = kb  + (size_t)BH * T * 64;
    short* xnT   = vb  + (size_t)BH * T * 64;           // [B][T][C]
    short* wqb   = xnT + (size_t)BATCH * T * C;
    short* wpb   = wqb + 768 * 256;
    short* opart = wpb + 256 * 256;                     // [4][BH][T][64] bf16
    float* lp    = (float*)(opart + (size_t)KSPLIT * BH * T * 64);  // [4][BH][T]
    float* gnp   = lp + (size_t)KSPLIT * BH * T;        // [64][4][2]

    prep_stats<<<dim3(512), 256, 0, stream>>>(w_qkv, w_proj, wqb, wpb, x, gnp);
    gn_norm<<<dim3(BATCH * G, 4), 256, 0, stream>>>(x, gn_scale, gn_bias, gnp, xnT);
    gemm_qkv<<<dim3(T/64, 12, BATCH), 256, 0, stream>>>(wqb, b_qkv, xnT, qb, kb, vb);
    attn_kernel<<<dim3(T/256, BH, KSPLIT), 512, 0, stream>>>(qb, kb, vb, opart, lp);
    gemm_proj<<<dim3(T/64, 4, BATCH), 256, 0, stream>>>(wpb, b_proj, opart, lp, x, out);
}